// Round 1
// baseline (320.543 us; speedup 1.0000x reference)
//
#include <hip/hip_runtime.h>

// Problem constants
constexpr int D0  = 11;
constexpr int Hh  = 200;
constexpr int Ww  = 176;
constexpr int HWC = Hh * Ww;        // 35200
constexpr int NV  = 16000;
constexpr int CIN = 128;
constexpr int CM  = 64;
constexpr int ND1 = 5;              // D after first stride-2 (VALID, k=3): (11-3)/2+1
constexpr int ND2 = 2;              // (5-3)/2+1
constexpr int MAXN1 = 32000;        // each voxel maps to <=2 level-1 slices
constexpr float EPS = 1e-5f;

// ---------------- setup kernels ----------------

__global__ __launch_bounds__(256) void scatter_k(const int* __restrict__ coors,
                                                 int* __restrict__ grid0) {
    int i = blockIdx.x * blockDim.x + threadIdx.x;
    if (i >= NV) return;
    const int4 c = reinterpret_cast<const int4*>(coors)[i];   // b,z,y,x
    grid0[c.y * HWC + c.z * Ww + c.w] = i;
}

// w[o][i][k] -> wt[k][i][o]   (O always 64)
__global__ __launch_bounds__(256) void transpose_all_k(
    const float* __restrict__ w1, const float* __restrict__ w2,
    const float* __restrict__ w3, const float* __restrict__ w4,
    const float* __restrict__ w5,
    float* __restrict__ w1t, float* __restrict__ w2t, float* __restrict__ w3t,
    float* __restrict__ w4t, float* __restrict__ w5t) {
    const float* src; float* dst; int I, K;
    switch (blockIdx.y) {
        case 0: src = w1; dst = w1t; I = 128; K = 27; break;
        case 1: src = w2; dst = w2t; I = 64;  K = 3;  break;
        case 2: src = w3; dst = w3t; I = 64;  K = 27; break;
        case 3: src = w4; dst = w4t; I = 64;  K = 27; break;
        default: src = w5; dst = w5t; I = 64; K = 3;  break;
    }
    int tot = 64 * I * K;
    int idx = blockIdx.x * blockDim.x + threadIdx.x;
    if (idx >= tot) return;
    int o = idx / (I * K);
    int r = idx % (I * K);
    int ii = r / K;
    int k  = r % K;
    dst[(k * I + ii) * 64 + o] = src[idx];
}

__global__ __launch_bounds__(256) void build_l1_k(const int* __restrict__ grid0,
                                                  int* __restrict__ grid1,
                                                  int* __restrict__ list1,
                                                  int* __restrict__ cnt) {
    int p = blockIdx.x * blockDim.x + threadIdx.x;
    if (p >= ND1 * HWC) return;
    int d1 = p / HWC, yx = p % HWC;
    int base = (2 * d1) * HWC + yx;
    bool occ = (grid0[base] >= 0) | (grid0[base + HWC] >= 0) | (grid0[base + 2 * HWC] >= 0);
    if (occ) {
        int s = atomicAdd(cnt, 1);
        grid1[p] = s;
        list1[s] = p;
    }
}

// ---------------- conv kernels (one wave per active output site) ----------------

__global__ __launch_bounds__(64) void conv1_k(const float* __restrict__ vf,
    const float* __restrict__ w1t, const int* __restrict__ coors,
    const int* __restrict__ grid0,
    const float* __restrict__ bg, const float* __restrict__ bb,
    const float* __restrict__ bm, const float* __restrict__ bv,
    float* __restrict__ f1) {
    int i = blockIdx.x;
    int o = threadIdx.x;      // output channel
    __shared__ int   jw[27];
    __shared__ float xs[CIN];
    const int4 c = reinterpret_cast<const int4*>(coors)[i];
    if (o < 27) {
        int kd = o / 9, r = o % 9, kh = r / 3, kw = r % 3;
        int zz = c.y + kd - 1, yy = c.z + kh - 1, xx = c.w + kw - 1;
        int j = -1;
        if ((unsigned)zz < (unsigned)D0 && (unsigned)yy < (unsigned)Hh && (unsigned)xx < (unsigned)Ww)
            j = grid0[zz * HWC + yy * Ww + xx];
        jw[o] = j;
    }
    __syncthreads();
    float a0 = 0.f, a1 = 0.f, a2 = 0.f, a3 = 0.f;
    for (int k = 0; k < 27; ++k) {
        int j = jw[k];                 // uniform across the wave
        if (j < 0) continue;
        __syncthreads();
        xs[o]      = vf[j * CIN + o];
        xs[o + 64] = vf[j * CIN + 64 + o];
        __syncthreads();
        const float* wp = w1t + k * (CIN * 64) + o;
        #pragma unroll
        for (int cc = 0; cc < CIN; cc += 4) {
            a0 = fmaf(xs[cc],     wp[(cc)     * 64], a0);
            a1 = fmaf(xs[cc + 1], wp[(cc + 1) * 64], a1);
            a2 = fmaf(xs[cc + 2], wp[(cc + 2) * 64], a2);
            a3 = fmaf(xs[cc + 3], wp[(cc + 3) * 64], a3);
        }
    }
    float acc = (a0 + a1) + (a2 + a3);
    float g = bg[o], be = bb[o], mu = bm[o], va = bv[o];
    float sc = g / sqrtf(va + EPS);
    float sh = be - mu * sc;
    f1[i * 64 + o] = fmaxf(fmaf(acc, sc, sh), 0.f);
}

__global__ __launch_bounds__(64) void conv2_k(const float* __restrict__ f1,
    const float* __restrict__ w2t, const int* __restrict__ list1,
    const int* __restrict__ grid0, const int* __restrict__ cnt,
    const float* __restrict__ bg, const float* __restrict__ bb,
    const float* __restrict__ bm, const float* __restrict__ bv,
    float* __restrict__ f2) {
    int n1 = cnt[0];
    int b = blockIdx.x;
    if (b >= n1) return;
    int o = threadIdx.x;
    __shared__ float xs[64];
    int p = list1[b];
    int d1 = p / HWC, yx = p % HWC;
    float a0 = 0.f, a1 = 0.f, a2 = 0.f, a3 = 0.f;
    for (int k = 0; k < 3; ++k) {
        int j = grid0[(2 * d1 + k) * HWC + yx];   // uniform across wave
        if (j < 0) continue;
        __syncthreads();
        xs[o] = f1[j * 64 + o];
        __syncthreads();
        const float* wp = w2t + k * (64 * 64) + o;
        #pragma unroll
        for (int cc = 0; cc < 64; cc += 4) {
            a0 = fmaf(xs[cc],     wp[(cc)     * 64], a0);
            a1 = fmaf(xs[cc + 1], wp[(cc + 1) * 64], a1);
            a2 = fmaf(xs[cc + 2], wp[(cc + 2) * 64], a2);
            a3 = fmaf(xs[cc + 3], wp[(cc + 3) * 64], a3);
        }
    }
    float acc = (a0 + a1) + (a2 + a3);
    float g = bg[o], be = bb[o], mu = bm[o], va = bv[o];
    float sc = g / sqrtf(va + EPS);
    float sh = be - mu * sc;
    f2[b * 64 + o] = fmaxf(fmaf(acc, sc, sh), 0.f);
}

// conv3 / conv4: 3x3x3 pad 1 on the level-1 grid, 64->64
__global__ __launch_bounds__(64) void conv27_k(const float* __restrict__ fin,
    const float* __restrict__ wt, const int* __restrict__ list1,
    const int* __restrict__ grid1, const int* __restrict__ cnt,
    const float* __restrict__ bg, const float* __restrict__ bb,
    const float* __restrict__ bm, const float* __restrict__ bv,
    float* __restrict__ fout) {
    int n1 = cnt[0];
    int b = blockIdx.x;
    if (b >= n1) return;
    int o = threadIdx.x;
    __shared__ int   jw[27];
    __shared__ float xs[64];
    int p = list1[b];
    int d1 = p / HWC, yx = p % HWC, y = yx / Ww, x = yx % Ww;
    if (o < 27) {
        int kd = o / 9, r = o % 9, kh = r / 3, kw = r % 3;
        int dd = d1 + kd - 1, yy = y + kh - 1, xx = x + kw - 1;
        int s = -1;
        if ((unsigned)dd < (unsigned)ND1 && (unsigned)yy < (unsigned)Hh && (unsigned)xx < (unsigned)Ww)
            s = grid1[dd * HWC + yy * Ww + xx];
        jw[o] = s;
    }
    __syncthreads();
    float a0 = 0.f, a1 = 0.f, a2 = 0.f, a3 = 0.f;
    for (int k = 0; k < 27; ++k) {
        int s = jw[k];
        if (s < 0) continue;
        __syncthreads();
        xs[o] = fin[s * 64 + o];
        __syncthreads();
        const float* wp = wt + k * (64 * 64) + o;
        #pragma unroll
        for (int cc = 0; cc < 64; cc += 4) {
            a0 = fmaf(xs[cc],     wp[(cc)     * 64], a0);
            a1 = fmaf(xs[cc + 1], wp[(cc + 1) * 64], a1);
            a2 = fmaf(xs[cc + 2], wp[(cc + 2) * 64], a2);
            a3 = fmaf(xs[cc + 3], wp[(cc + 3) * 64], a3);
        }
    }
    float acc = (a0 + a1) + (a2 + a3);
    float g = bg[o], be = bb[o], mu = bm[o], va = bv[o];
    float sc = g / sqrtf(va + EPS);
    float sh = be - mu * sc;
    fout[b * 64 + o] = fmaxf(fmaf(acc, sc, sh), 0.f);
}

__global__ __launch_bounds__(64) void conv5_k(const float* __restrict__ f4,
    const float* __restrict__ w5t, const int* __restrict__ grid1,
    const float* __restrict__ bg, const float* __restrict__ bb,
    const float* __restrict__ bm, const float* __restrict__ bv,
    float* __restrict__ out) {
    int p = blockIdx.x;             // 0 .. 2*HWC-1
    int o = threadIdx.x;
    int d2 = p / HWC, yx = p % HWC;
    int s0 = grid1[(2 * d2)     * HWC + yx];
    int s1 = grid1[(2 * d2 + 1) * HWC + yx];
    int s2 = grid1[(2 * d2 + 2) * HWC + yx];
    if (s0 < 0 && s1 < 0 && s2 < 0) return;     // output pre-zeroed
    __shared__ float xs[64];
    float a0 = 0.f, a1 = 0.f, a2 = 0.f, a3 = 0.f;
    int ss[3] = {s0, s1, s2};
    for (int k = 0; k < 3; ++k) {
        int s = ss[k];
        if (s < 0) continue;
        __syncthreads();
        xs[o] = f4[s * 64 + o];
        __syncthreads();
        const float* wp = w5t + k * (64 * 64) + o;
        #pragma unroll
        for (int cc = 0; cc < 64; cc += 4) {
            a0 = fmaf(xs[cc],     wp[(cc)     * 64], a0);
            a1 = fmaf(xs[cc + 1], wp[(cc + 1) * 64], a1);
            a2 = fmaf(xs[cc + 2], wp[(cc + 2) * 64], a2);
            a3 = fmaf(xs[cc + 3], wp[(cc + 3) * 64], a3);
        }
    }
    float acc = (a0 + a1) + (a2 + a3);
    float g = bg[o], be = bb[o], mu = bm[o], va = bv[o];
    float sc = g / sqrtf(va + EPS);
    float sh = be - mu * sc;
    // output: (1, 64, 2, 200, 176) reshaped to (1, 128, 200, 176): channel = o*2 + d2
    out[(o * ND2 + d2) * HWC + yx] = fmaxf(fmaf(acc, sc, sh), 0.f);
}

// ---------------- launch ----------------

extern "C" void kernel_launch(void* const* d_in, const int* in_sizes, int n_in,
                              void* d_out, int out_size, void* d_ws, size_t ws_size,
                              hipStream_t stream) {
    const float* vf = (const float*)d_in[0];
    const float* w1 = (const float*)d_in[1];
    const float* w2 = (const float*)d_in[2];
    const float* w3 = (const float*)d_in[3];
    const float* w4 = (const float*)d_in[4];
    const float* w5 = (const float*)d_in[5];
    const float* bg = (const float*)d_in[6];
    const float* bb = (const float*)d_in[7];
    const float* bm = (const float*)d_in[8];
    const float* bv = (const float*)d_in[9];
    const int* coors = (const int*)d_in[10];
    float* out = (float*)d_out;

    char* ws = (char*)d_ws;
    size_t off = 0;
    auto take = [&](size_t n) -> void* {
        void* pp = ws + off;
        off += (n + 255) & ~(size_t)255;
        return pp;
    };
    int*   grid0 = (int*)take(D0 * HWC * 4);          // 1.55 MB
    int*   grid1 = (int*)take(ND1 * HWC * 4);         // 0.70 MB
    int*   list1 = (int*)take(MAXN1 * 4);
    int*   cnt   = (int*)take(256);
    float* w1t   = (float*)take(27 * CIN * 64 * 4);
    float* w2t   = (float*)take(3 * 64 * 64 * 4);
    float* w3t   = (float*)take(27 * 64 * 64 * 4);
    float* w4t   = (float*)take(27 * 64 * 64 * 4);
    float* w5t   = (float*)take(3 * 64 * 64 * 4);
    float* f1    = (float*)take((size_t)NV * 64 * 4);
    float* f2    = (float*)take((size_t)MAXN1 * 64 * 4);
    float* f3    = (float*)take((size_t)MAXN1 * 64 * 4);
    float* f4    = (float*)take((size_t)MAXN1 * 64 * 4);

    hipMemsetAsync(grid0, 0xFF, (size_t)D0 * HWC * 4, stream);   // -1
    hipMemsetAsync(grid1, 0xFF, (size_t)ND1 * HWC * 4, stream);  // -1
    hipMemsetAsync(cnt, 0, 256, stream);
    hipMemsetAsync(out, 0, (size_t)out_size * 4, stream);

    scatter_k<<<(NV + 255) / 256, 256, 0, stream>>>(coors, grid0);

    dim3 tg((27 * CIN * 64 + 255) / 256, 5);
    transpose_all_k<<<tg, 256, 0, stream>>>(w1, w2, w3, w4, w5, w1t, w2t, w3t, w4t, w5t);

    build_l1_k<<<(ND1 * HWC + 255) / 256, 256, 0, stream>>>(grid0, grid1, list1, cnt);

    conv1_k<<<NV, 64, 0, stream>>>(vf, w1t, coors, grid0, bg, bb, bm, bv, f1);
    conv2_k<<<MAXN1, 64, 0, stream>>>(f1, w2t, list1, grid0, cnt,
                                      bg + 64, bb + 64, bm + 64, bv + 64, f2);
    conv27_k<<<MAXN1, 64, 0, stream>>>(f2, w3t, list1, grid1, cnt,
                                       bg + 128, bb + 128, bm + 128, bv + 128, f3);
    conv27_k<<<MAXN1, 64, 0, stream>>>(f3, w4t, list1, grid1, cnt,
                                       bg + 192, bb + 192, bm + 192, bv + 192, f4);
    conv5_k<<<ND2 * HWC, 64, 0, stream>>>(f4, w5t, grid1,
                                          bg + 256, bb + 256, bm + 256, bv + 256, out);
}